// Round 9
// baseline (247.456 us; speedup 1.0000x reference)
//
#include <hip/hip_runtime.h>

typedef unsigned short u16;
typedef unsigned long long u64;

// ---------------- problem constants ----------------
constexpr int cB = 4, cT = 40, cR = 2000, cA = 36864;
constexpr int cH = 64, cW = 64, cC = 256, cPP = 7;
constexpr int cNCLS = 21, cNPOS = 64, cNNEG = 192, cDH = 1024;
constexpr int cD = cPP * cPP * cC;          // 12544
constexpr int cBA = cB * cA;                // 147456
constexpr int cBR = cB * cR;                // 8000
constexpr int NW64 = cBA / 64;              // 2304 mask words
constexpr int SPLITS = 14;                  // k-splits for gemm1
constexpr int KCH = cD / SPLITS;            // 896 = 7*128
constexpr int BK = 128;                     // k per iteration
constexpr int NITER = KCH / BK;             // 7
constexpr unsigned POSKEY = 0x007FFFFFu;    // f2key(-inf): marks iou>0.5

// ---------------- ws layout (bytes); ws = 256 MiB, no aliasing ----------------
constexpr size_t O_TIDX  = 0;                         // cBA int      -> 589824
constexpr size_t O_MASKW = 589824;                    // 2304 u64     -> 608256
constexpr size_t O_KEYS  = 608256;                    // 8000 u32     -> 640256
constexpr size_t O_RIDXG = 640256;                    // 8000 int     -> 672256
constexpr size_t O_SEL   = 672256;                    // 256 int
constexpr size_t O_CLS   = 673280;                    // 256 int
constexpr size_t O_ROIS  = 674304;                    // 256*4 f32
constexpr size_t O_TGT   = 678400;                    // 64*4 f32
constexpr size_t O_FMT   = 1048576;                   // B*HW*C bf16 = 8388608
constexpr size_t O_FEAT  = O_FMT + 8388608;           // 256*12544 bf16 = 6422528
constexpr size_t O_CPART = O_FEAT + 6422528;          // 14*256*1024 f32 = 14680064

// ---------------- helpers ----------------
__device__ __forceinline__ float b2f(u16 u) {
  return __uint_as_float(((unsigned)u) << 16);
}
__device__ __forceinline__ u16 f2b(float f) {  // f32 -> bf16 bits (RNE)
  unsigned x = __float_as_uint(f);
  unsigned r = x + 0x7FFFu + ((x >> 16) & 1u);
  return (u16)(r >> 16);
}
__device__ __forceinline__ unsigned f2key(float f) {  // monotonic f32->u32
  unsigned b = __float_as_uint(f);
  return b ^ ((b & 0x80000000u) ? 0xFFFFFFFFu : 0x80000000u);
}

typedef __attribute__((ext_vector_type(8))) short short8;
typedef __attribute__((ext_vector_type(4))) float f32x4;

// ================= K1: fused RPN IoU + RCNN IoU + feature transpose ========
// blocks 0..575: RPN; 576..607: RCNN; 608..1631: fm (B,C,HW) f32 -> (B,HW,C) bf16
__global__ __launch_bounds__(256) void k_front(
    const float* __restrict__ bboxes, const float* __restrict__ anchors,
    const float* __restrict__ nms_reg, const float* __restrict__ fm,
    int* __restrict__ tidx, u64* __restrict__ maskw,
    unsigned* __restrict__ keys, int* __restrict__ ridxg,
    u16* __restrict__ fmt) {
  __shared__ float sfm[64 * 65];
  int bid = blockIdx.x;
  if (bid < 576) {
    float* sb = sfm;
    int b = bid / 144;
    if (threadIdx.x < cT * 4) sb[threadIdx.x] = bboxes[b * cT * 4 + threadIdx.x];
    __syncthreads();
    int i = bid * 256 + threadIdx.x;
    int a = i - b * cA;
    float4 av = ((const float4*)anchors)[a];
    float at = av.x, al = av.y, ab = av.z, ar = av.w;
    float area_a = (ab - at) * (ar - al);
    float best = -1.0f; int bi = 0;
    for (int t = 0; t < cT; ++t) {
      float bt = sb[t * 4], bl = sb[t * 4 + 1], bbv = sb[t * 4 + 2], brv = sb[t * 4 + 3];
      float ih = fmaxf(fminf(bbv, ab) - fmaxf(bt, at), 0.0f);
      float iw = fmaxf(fminf(brv, ar) - fmaxf(bl, al), 0.0f);
      float inter = ih * iw;
      float a1 = (bbv - bt) * (brv - bl);
      float iou = inter / (a1 + area_a - inter);
      if (iou > best) { best = iou; bi = t; }
    }
    tidx[i] = bi;
    u64 bal = __ballot(best > 0.5f);
    if ((threadIdx.x & 63) == 0) maskw[i >> 6] = bal;
  } else if (bid < 608) {
    float* sb = sfm;
    for (int j = threadIdx.x; j < cB * cT * 4; j += 256) sb[j] = bboxes[j];
    __syncthreads();
    int i = (bid - 576) * 256 + threadIdx.x;
    if (i >= cBR) return;
    int b = i / cR;
    float4 nv = ((const float4*)nms_reg)[i];
    float nt = nv.x, nl = nv.y, nb = nv.z, nr = nv.w;
    float area_n = (nb - nt) * (nr - nl);
    float best = -1.0f; int bi = 0;
    for (int t = 0; t < cT; ++t) {
      const float* bx = &sb[(b * cT + t) * 4];
      float ih = fmaxf(fminf(bx[2], nb) - fmaxf(bx[0], nt), 0.0f);
      float iw = fmaxf(fminf(bx[3], nr) - fmaxf(bx[1], nl), 0.0f);
      float inter = ih * iw;
      float a1 = (bx[2] - bx[0]) * (bx[3] - bx[1]);
      float iou = inter / (a1 + area_n - inter);
      if (iou > best) { best = iou; bi = t; }
    }
    keys[i] = (best <= 0.5f) ? f2key(best) : POSKEY;
    ridxg[i] = bi;
  } else {
    int f = bid - 608;
    int b = f >> 8;
    int c0 = ((f >> 6) & 3) * 64;
    int p0 = (f & 63) * 64;
    int t = threadIdx.x;
    int pL = (t & 15) * 4, cL = t >> 4;
    #pragma unroll
    for (int i = 0; i < 4; ++i) {
      int c = cL + i * 16;
      float4 v = *(const float4*)&fm[((size_t)b * cC + c0 + c) * (cH * cW) + p0 + pL];
      sfm[c * 65 + pL] = v.x; sfm[c * 65 + pL + 1] = v.y;
      sfm[c * 65 + pL + 2] = v.z; sfm[c * 65 + pL + 3] = v.w;
    }
    __syncthreads();
    int pW = t >> 2, cg = (t & 3) * 16;
    unsigned pk[8];
    #pragma unroll
    for (int j = 0; j < 8; ++j) {
      unsigned lo = f2b(sfm[(cg + 2 * j) * 65 + pW]);
      unsigned hi = f2b(sfm[(cg + 2 * j + 1) * 65 + pW]);
      pk[j] = lo | (hi << 16);
    }
    u16* dst = &fmt[((size_t)b * (cH * cW) + p0 + pW) * cC + c0 + cg];
    *(uint4*)dst = *(uint4*)&pk[0];
    *(uint4*)(dst + 8) = *(uint4*)&pk[4];
  }
}

// ================= K2: fused selection (block 0: RPN, block 1: RCNN) ========
__global__ __launch_bounds__(1024) void k_select(
    const u64* __restrict__ maskw, const int* __restrict__ tidx,
    const float* __restrict__ rpn_cls, const float* __restrict__ rpn_reg,
    const float* __restrict__ bboxes, const float* __restrict__ anchors,
    const unsigned* __restrict__ keysg, const int* __restrict__ ridxg,
    const float* __restrict__ nms_reg, const int* __restrict__ classes,
    int* __restrict__ sel, int* __restrict__ cls_s,
    float* __restrict__ rois, float* __restrict__ tgt,
    float* __restrict__ out) {
  __shared__ __align__(16) char smem[50688];
  __shared__ float s_scalF[2];
  __shared__ int s_scalI[3];
  int tid = threadIdx.x, lane = tid & 63, w = tid >> 6;
  u64 lmask = (1ULL << lane) - 1ULL;

  if (blockIdx.x == 0) {
    if (tid < 4) out[2 + tid] = 0.0f;   // zero accumulators for k_heads
    u64* s_w   = (u64*)smem;
    int* s_pre = (int*)(smem + 18432);
    int* s_cw  = (int*)(smem + 19008);
    int* s_pos = (int*)(smem + 19584);
    int* s_neg = (int*)(smem + 20096);
    for (int k = tid; k < NW64; k += 1024) s_w[k] = maskw[k];
    if (tid < 128) s_pos[tid] = 0;
    if (tid < 252) s_neg[tid] = 0;
    if (tid == 0) { s_scalF[0] = 0.0f; s_scalF[1] = 0.0f; }
    __syncthreads();
    if (tid < 144) {
      int c = 0;
      #pragma unroll
      for (int k2 = 0; k2 < 16; ++k2) c += __popcll(s_w[tid * 16 + k2]);
      s_cw[tid] = c;
    }
    __syncthreads();
    if (tid == 0) {
      int run = 0;
      for (int ch = 0; ch < 144; ++ch) { s_pre[ch] = run; run += s_cw[ch]; }
    }
    __syncthreads();
    for (int ch = w; ch < 144; ch += 16) {
      int pbase = s_pre[ch];
      int nbase = ch * 1024 - pbase;
      if (pbase >= 128 && nbase >= 252) continue;
      int pc = 0;
      #pragma unroll
      for (int s2 = 0; s2 < 16; ++s2) {
        u64 word = s_w[ch * 16 + s2];
        bool m = (word >> lane) & 1ULL;
        int prefP = __popcll(word & lmask);
        int idx = ch * 1024 + s2 * 64 + lane;
        if (m) {
          int g = pbase + pc + prefP;
          if (g < 128) s_pos[g] = idx;
        } else {
          int g = nbase + (s2 * 64 + lane) - (pc + prefP);
          if (g < 252) s_neg[g] = idx;
        }
        pc += __popcll(word);
      }
    }
    __syncthreads();
    if (tid < 380) {
      int flat; float lbl;
      if (tid < 128) { flat = s_pos[tid]; lbl = 1.0f; }
      else           { flat = s_neg[tid - 128]; lbl = 0.0f; }
      float l = rpn_cls[flat];
      float term = fmaxf(l, 0.0f) - l * lbl + log1pf(expf(-fabsf(l)));
      atomicAdd(&s_scalF[0], term);
    }
    if (tid < 512) {
      int j = tid >> 2, c = tid & 3;
      int flat = s_pos[j];
      int b = flat / cA, a = flat - b * cA;
      int t = tidx[flat];
      float p = rpn_reg[flat * 4 + c];
      float tg = bboxes[(b * cT + t) * 4 + c] - anchors[a * 4 + c];
      float d = fabsf(p - tg);
      float sl = (d < 1.0f) ? 0.5f * d * d : d - 0.5f;
      atomicAdd(&s_scalF[1], sl);
    }
    __syncthreads();
    if (tid == 0) {
      out[0] = s_scalF[0] / 380.0f;
      out[1] = s_scalF[1] / 512.0f / 4.0f;
    }
  } else {
    unsigned* s_key = (unsigned*)smem;
    int* s_hist = (int*)(smem + 32000);
    int* s_pc   = (int*)(smem + 48384);
    int* s_wsum = (int*)(smem + 48896);
    int* s_wsuf = (int*)(smem + 48960);
    int* s_posr = (int*)(smem + 49024);
    int* s_negr = (int*)(smem + 49280);

    for (int i = tid; i < cBR; i += 1024) s_key[i] = keysg[i];
    if (tid < 64) s_posr[tid] = 0;
    __syncthreads();

    {
      int myv = 0; int mypre[8];
      #pragma unroll
      for (int p = 0; p < 8; ++p) {
        int i = p * 1024 + tid;
        bool v = (i < cBR) && (s_key[i] == POSKEY);
        u64 bal = __ballot(v);
        if (lane == 0) s_pc[p * 16 + w] = __popcll(bal);
        mypre[p] = __popcll(bal & lmask);
        myv |= v ? (1 << p) : 0;
      }
      __syncthreads();
      if (tid == 0) {
        int run = 0;
        for (int k = 0; k < 128; ++k) { int t = s_pc[k]; s_pc[k] = run; run += t; }
      }
      __syncthreads();
      #pragma unroll
      for (int p = 0; p < 8; ++p) {
        if (myv & (1 << p)) {
          int g = s_pc[p * 16 + w] + mypre[p];
          if (g < 64) s_posr[g] = p * 1024 + tid;
        }
      }
    }

    unsigned thr = 0; int G = 0;
    int need = cNNEG;
    #pragma unroll
    for (int lvl = 0; lvl < 3; ++lvl) {
      __syncthreads();
      #pragma unroll
      for (int k = 0; k < 4; ++k) s_hist[tid * 4 + k] = 0;
      __syncthreads();
      #pragma unroll
      for (int p = 0; p < 8; ++p) {
        int i = p * 1024 + tid;
        if (i < cBR) {
          unsigned key = s_key[i];
          int bkt = -1;
          if (lvl == 0) bkt = key >> 20;
          else if (lvl == 1) { if ((key >> 20) == (thr >> 20)) bkt = (key >> 8) & 0xFFF; }
          else { if ((key >> 8) == (thr >> 8)) bkt = (key & 0xFF) << 4; }
          if (bkt >= 0) atomicAdd(&s_hist[bkt], 1);
        }
      }
      __syncthreads();
      int local0 = s_hist[tid * 4 + 0], local1 = s_hist[tid * 4 + 1];
      int local2 = s_hist[tid * 4 + 2], local3 = s_hist[tid * 4 + 3];
      int lsum = local0 + local1 + local2 + local3;
      int x = lsum;
      #pragma unroll
      for (int off = 1; off < 64; off <<= 1) {
        int t = __shfl_down(x, off, 64);
        if (lane + off < 64) x += t;
      }
      if (lane == 0) s_wsum[w] = x;
      __syncthreads();
      if (tid == 0) {
        int run = 0;
        for (int wi = 15; wi >= 0; --wi) { s_wsuf[wi] = run; run += s_wsum[wi]; }
      }
      __syncthreads();
      int above = s_wsuf[w] + (x - lsum);
      int run = above;
      int loc[4] = {local3, local2, local1, local0};
      #pragma unroll
      for (int j = 0; j < 4; ++j) {
        int S = run + loc[j];
        if (run < need && S >= need) { s_scalI[0] = tid * 4 + (3 - j); s_scalI[1] = run; }
        run = S;
      }
      __syncthreads();
      int bS = s_scalI[0], ov = s_scalI[1];
      if (lvl == 0) thr = ((unsigned)bS) << 20;
      else if (lvl == 1) thr |= ((unsigned)bS) << 8;
      else thr |= ((unsigned)bS) >> 4;
      G += ov;
      need -= ov;
    }

    if (tid == 0) s_scalI[2] = 0;
    __syncthreads();
    #pragma unroll
    for (int p = 0; p < 8; ++p) {
      int i = p * 1024 + tid;
      if (i < cBR && s_key[i] > thr) {
        int slot = atomicAdd(&s_scalI[2], 1);
        s_negr[slot] = i;
      }
    }
    {
      __syncthreads();
      int myv = 0; int mypre[8];
      #pragma unroll
      for (int p = 0; p < 8; ++p) {
        int i = p * 1024 + tid;
        bool v = (i < cBR) && (s_key[i] == thr);
        u64 bal = __ballot(v);
        if (lane == 0) s_pc[p * 16 + w] = __popcll(bal);
        mypre[p] = __popcll(bal & lmask);
        myv |= v ? (1 << p) : 0;
      }
      __syncthreads();
      if (tid == 0) {
        int run = 0;
        for (int k = 0; k < 128; ++k) { int t = s_pc[k]; s_pc[k] = run; run += t; }
      }
      __syncthreads();
      #pragma unroll
      for (int p = 0; p < 8; ++p) {
        if (myv & (1 << p)) {
          int g = s_pc[p * 16 + w] + mypre[p];
          if (g < need) s_negr[G + g] = p * 1024 + tid;
        }
      }
    }
    __syncthreads();

    if (tid < 256) {
      int flat = (tid < 64) ? s_posr[tid] : s_negr[tid - 64];
      sel[tid] = flat;
      int b = flat / cR;
      #pragma unroll
      for (int c = 0; c < 4; ++c) rois[tid * 4 + c] = nms_reg[flat * 4 + c];
      cls_s[tid] = (tid < 64) ? classes[b * cT + ridxg[flat]] : 0;
      if (tid < 64) {
        int mt = ridxg[flat];
        #pragma unroll
        for (int c = 0; c < 4; ++c) {
          float v = nms_reg[flat * 4 + c];
          float rr = ((c < 2) ? floorf(v * 16.0f) : ceilf(v * 16.0f)) / 16.0f;
          float mbv = bboxes[(b * cT + mt) * 4 + c];
          tgt[tid * 4 + c] = mbv - rr;
        }
      }
    }
  }
}

// ================= K3: ROI align (coalesced, one block per roi x bin-row) ===
__global__ void k_roi_pool(const u16* __restrict__ fmt, const float* __restrict__ rois,
                           const int* __restrict__ sel, u16* __restrict__ feat) {
  int j = blockIdx.x;
  int py = blockIdx.y;
  int c = threadIdx.x;
  int flat = sel[j];
  int n = flat / cR;
  float t = rois[j * 4 + 0], l = rois[j * 4 + 1];
  float bb = rois[j * 4 + 2], r = rois[j * 4 + 3];
  const u16* base = fmt + (size_t)n * (cH * cW) * cC;
  float gy = (py + 0.5f) / (float)cPP;
  float ys = fminf(fmaxf(t + gy * (bb - t), 0.0f), 63.0f);
  int y0 = (int)floorf(ys);
  int y1 = min(y0 + 1, 63);
  float wy = ys - (float)y0;
  #pragma unroll
  for (int px = 0; px < cPP; ++px) {
    float gx = (px + 0.5f) / (float)cPP;
    float xs = fminf(fmaxf(l + gx * (r - l), 0.0f), 63.0f);
    int x0 = (int)floorf(xs);
    int x1 = min(x0 + 1, 63);
    float wx = xs - (float)x0;
    float f00 = b2f(base[(y0 * cW + x0) * cC + c]);
    float f01 = b2f(base[(y0 * cW + x1) * cC + c]);
    float f10 = b2f(base[(y1 * cW + x0) * cC + c]);
    float f11 = b2f(base[(y1 * cW + x1) * cC + c]);
    float v = f00 * (1.0f - wy) * (1.0f - wx) + f01 * (1.0f - wy) * wx +
              f10 * wy * (1.0f - wx) + f11 * wy * wx;
    feat[((size_t)j * 49 + py * cPP + px) * cC + c] = f2b(v);
  }
}

// ================= K4: GEMM1 feat(256x12544 bf16) @ W1(12544x1024 f32) ======
// Grid (32 n, 14 ksplit, 4 m) = 1792 blocks. M=64, N=32, K=896, BK=128 -> 7 iters.
// XOR-swizzled LDS chunks (stride 128, no pad): reads 2-way (free), writes <=4-way.
// 20 independent VMEM loads in flight per thread per barrier.
__global__ __launch_bounds__(256) void k_gemm1(const u16* __restrict__ feat, const float* __restrict__ W1,
                                               float* __restrict__ Cpart) {
  __shared__ u16 As[64 * 128];
  __shared__ u16 Bs[32 * 128];
  int tid = threadIdx.x;
  int n0 = blockIdx.x * 32;
  int kb0 = blockIdx.y * KCH;
  int m0 = blockIdx.z * 64;
  int lane = tid & 63, w = tid >> 6;
  int r = lane & 15, q = lane >> 4;
  f32x4 acc[2] = {};

  int am = tid >> 2;                 // A row 0..63
  int aj0 = (tid & 3) * 4;           // first of 4 chunks (16B each)
  int bn = tid & 31;                 // B col
  int bkg = tid >> 5;                // 0..7, 16 k each

  uint4 ra[4];
  float rb[16];
  auto loadAB = [&](int it) {
    int kb = kb0 + it * BK;
    const u16* ap = &feat[(size_t)(m0 + am) * cD + kb];
    #pragma unroll
    for (int i = 0; i < 4; ++i) ra[i] = *(const uint4*)(ap + (aj0 + i) * 8);
    const float* bp = &W1[(size_t)(kb + bkg * 16) * cDH + n0 + bn];
    #pragma unroll
    for (int j = 0; j < 16; ++j) rb[j] = bp[(size_t)j * cDH];
  };

  loadAB(0);
  for (int it = 0; it < NITER; ++it) {
    __syncthreads();
    #pragma unroll
    for (int i = 0; i < 4; ++i) {
      int c = aj0 + i;
      *(uint4*)&As[am * 128 + ((c ^ (am & 15)) << 3)] = ra[i];
    }
    #pragma unroll
    for (int s = 0; s < 2; ++s) {
      union { u16 u[8]; uint4 v; } pb;
      #pragma unroll
      for (int j = 0; j < 8; ++j) pb.u[j] = f2b(rb[s * 8 + j]);
      int c = bkg * 2 + s;
      *(uint4*)&Bs[bn * 128 + ((c ^ (bn & 15)) << 3)] = pb.v;
    }
    __syncthreads();
    if (it + 1 < NITER) loadAB(it + 1);
    #pragma unroll
    for (int ks = 0; ks < 4; ++ks) {
      int ca = ks * 4 + q;
      short8 a = *(const short8*)&As[(w * 16 + r) * 128 + ((ca ^ r) << 3)];
      #pragma unroll
      for (int nt = 0; nt < 2; ++nt) {
        short8 bfr = *(const short8*)&Bs[(nt * 16 + r) * 128 + ((ca ^ r) << 3)];
        acc[nt] = __builtin_amdgcn_mfma_f32_16x16x32_bf16(a, bfr, acc[nt], 0, 0, 0);
      }
    }
  }

  float* Cp = Cpart + (size_t)blockIdx.y * 256 * cDH;
  #pragma unroll
  for (int nt = 0; nt < 2; ++nt) {
    #pragma unroll
    for (int rg = 0; rg < 4; ++rg) {
      int row = m0 + w * 16 + q * 4 + rg;
      int col = n0 + nt * 16 + r;
      Cp[(size_t)row * cDH + col] = acc[nt][rg];
    }
  }
}

// ================= K5: heads + final losses (one block per roi row) =========
__global__ __launch_bounds__(256) void k_heads(
    const float* __restrict__ Cpart, const float* __restrict__ b1,
    const float* __restrict__ Wr, const float* __restrict__ br,
    const float* __restrict__ Wc, const float* __restrict__ bc,
    const int* __restrict__ cls_s, const float* __restrict__ tgt,
    float* __restrict__ out) {
  __shared__ float sacc[25];
  int row = blockIdx.x, tid = threadIdx.x, lane = tid & 63;
  if (tid < 25) sacc[tid] = 0.0f;
  __syncthreads();
  int k0 = tid * 4;
  float4 h = *(const float4*)&b1[k0];
  #pragma unroll
  for (int s = 0; s < SPLITS; ++s) {
    float4 c = *(const float4*)&Cpart[(size_t)s * 256 * cDH + (size_t)row * cDH + k0];
    h.x += c.x; h.y += c.y; h.z += c.z; h.w += c.w;
  }
  float hv[4] = {fmaxf(h.x, 0.f), fmaxf(h.y, 0.f), fmaxf(h.z, 0.f), fmaxf(h.w, 0.f)};
  float part[25];
  #pragma unroll
  for (int c = 0; c < 25; ++c) part[c] = 0.0f;
  #pragma unroll
  for (int j = 0; j < 4; ++j) {
    float4 wr = *(const float4*)&Wr[(k0 + j) * 4];
    part[0] += hv[j] * wr.x; part[1] += hv[j] * wr.y;
    part[2] += hv[j] * wr.z; part[3] += hv[j] * wr.w;
    const float* wc = &Wc[(k0 + j) * 21];
    #pragma unroll
    for (int c = 0; c < 21; ++c) part[4 + c] += hv[j] * wc[c];
  }
  #pragma unroll
  for (int off = 32; off; off >>= 1) {
    #pragma unroll
    for (int c = 0; c < 25; ++c) part[c] += __shfl_down(part[c], off, 64);
  }
  if (lane == 0) {
    #pragma unroll
    for (int c = 0; c < 25; ++c) atomicAdd(&sacc[c], part[c]);
  }
  __syncthreads();
  if (tid == 0) {
    int cls = cls_s[row];
    float m = -INFINITY;
    float vals[21];
    #pragma unroll
    for (int c = 0; c < 21; ++c) { vals[c] = sacc[4 + c] + bc[c]; m = fmaxf(m, vals[c]); }
    float sum = 0.0f;
    #pragma unroll
    for (int c = 0; c < 21; ++c) sum += expf(vals[c] - m);
    float lse = m + logf(sum);
    atomicAdd(&out[2], (lse - vals[cls]) * (1.0f / 256.0f));
    if (row < 64) {
      int am2 = 0; float bv = vals[0];
      #pragma unroll
      for (int c = 1; c < 21; ++c) if (vals[c] > bv) { bv = vals[c]; am2 = c; }
      if (am2 == cls) atomicAdd(&out[4], 1.0f / 64.0f);
    }
  }
  if (tid == 1 && row < 64) {
    float sl = 0.0f, of = 0.0f;
    #pragma unroll
    for (int c = 0; c < 4; ++c) {
      float d = fabsf((sacc[c] + br[c]) - tgt[row * 4 + c]);
      sl += (d < 1.0f) ? 0.5f * d * d : d - 0.5f;
      of += d;
    }
    atomicAdd(&out[3], sl * (1.0f / 256.0f));
    atomicAdd(&out[5], of * (1.0f / 256.0f));
  }
}

// ================= launch =================
extern "C" void kernel_launch(void* const* d_in, const int* in_sizes, int n_in,
                              void* d_out, int out_size, void* d_ws, size_t ws_size,
                              hipStream_t stream) {
  const float* nms_reg = (const float*)d_in[0];
  const float* fm      = (const float*)d_in[2];
  const float* bboxes  = (const float*)d_in[3];
  const int*   classes = (const int*)d_in[4];
  const float* anchors = (const float*)d_in[5];
  const float* rpn_reg = (const float*)d_in[6];
  const float* rpn_cls = (const float*)d_in[7];
  const float* W1      = (const float*)d_in[8];
  const float* b1      = (const float*)d_in[9];
  const float* Wr      = (const float*)d_in[10];
  const float* br      = (const float*)d_in[11];
  const float* Wc      = (const float*)d_in[12];
  const float* bc      = (const float*)d_in[13];
  float* out = (float*)d_out;
  char* ws = (char*)d_ws;

  int*      tidx  = (int*)(ws + O_TIDX);
  u64*      maskw = (u64*)(ws + O_MASKW);
  unsigned* keys  = (unsigned*)(ws + O_KEYS);
  int*      ridxg = (int*)(ws + O_RIDXG);
  int*      sel   = (int*)(ws + O_SEL);
  int*      clss  = (int*)(ws + O_CLS);
  float*    rois  = (float*)(ws + O_ROIS);
  float*    tgt   = (float*)(ws + O_TGT);
  u16*      fmt   = (u16*)(ws + O_FMT);
  u16*      feat  = (u16*)(ws + O_FEAT);
  float*    Cpart = (float*)(ws + O_CPART);

  k_front<<<608 + 1024, 256, 0, stream>>>(bboxes, anchors, nms_reg, fm,
                                          tidx, maskw, keys, ridxg, fmt);
  k_select<<<2, 1024, 0, stream>>>(maskw, tidx, rpn_cls, rpn_reg, bboxes, anchors,
                                   keys, ridxg, nms_reg, classes, sel, clss, rois, tgt, out);
  k_roi_pool<<<dim3(256, cPP), 256, 0, stream>>>(fmt, rois, sel, feat);
  k_gemm1<<<dim3(32, SPLITS, 4), 256, 0, stream>>>(feat, W1, Cpart);
  k_heads<<<256, 256, 0, stream>>>(Cpart, b1, Wr, br, Wc, bc, clss, tgt, out);
}

// Round 10
// 190.683 us; speedup vs baseline: 1.2977x; 1.2977x over previous
//
#include <hip/hip_runtime.h>

typedef unsigned short u16;
typedef unsigned long long u64;

// ---------------- problem constants ----------------
constexpr int cB = 4, cT = 40, cR = 2000, cA = 36864;
constexpr int cH = 64, cW = 64, cC = 256, cPP = 7;
constexpr int cNCLS = 21, cNPOS = 64, cNNEG = 192, cDH = 1024;
constexpr int cD = cPP * cPP * cC;          // 12544
constexpr int cBA = cB * cA;                // 147456
constexpr int cBR = cB * cR;                // 8000
constexpr int NW64 = cBA / 64;              // 2304 mask words
constexpr int SPLITS = 14;                  // k-splits for gemm1
constexpr int KCH = cD / SPLITS;            // 896 = 14*64
constexpr int BK = 64;                      // k per iteration
constexpr int NITER = KCH / BK;             // 14
constexpr unsigned POSKEY = 0x007FFFFFu;    // f2key(-inf): marks iou>0.5

// ---------------- ws layout (bytes); no aliasing ----------------
constexpr size_t O_TIDX  = 0;                         // cBA int      -> 589824
constexpr size_t O_MASKW = 589824;                    // 2304 u64     -> 608256
constexpr size_t O_KEYS  = 608256;                    // 8000 u32     -> 640256
constexpr size_t O_RIDXG = 640256;                    // 8000 int     -> 672256
constexpr size_t O_SEL   = 672256;                    // 256 int
constexpr size_t O_CLS   = 673280;                    // 256 int
constexpr size_t O_ROIS  = 674304;                    // 256*4 f32
constexpr size_t O_TGT   = 678400;                    // 64*4 f32
constexpr size_t O_FMT   = 1048576;                   // B*HW*C bf16 = 8388608
constexpr size_t O_FEAT  = O_FMT + 8388608;           // 256*12544 bf16 = 6422528
constexpr size_t O_CPART = O_FEAT + 6422528;          // 14*256*1024 f32 = 14680064

// ---------------- helpers ----------------
__device__ __forceinline__ float b2f(u16 u) {
  return __uint_as_float(((unsigned)u) << 16);
}
__device__ __forceinline__ u16 f2b(float f) {  // f32 -> bf16 bits (RNE)
  unsigned x = __float_as_uint(f);
  unsigned r = x + 0x7FFFu + ((x >> 16) & 1u);
  return (u16)(r >> 16);
}
__device__ __forceinline__ unsigned f2key(float f) {  // monotonic f32->u32
  unsigned b = __float_as_uint(f);
  return b ^ ((b & 0x80000000u) ? 0xFFFFFFFFu : 0x80000000u);
}

typedef __attribute__((ext_vector_type(8))) short short8;
typedef __attribute__((ext_vector_type(4))) float f32x4;

// ================= K1: fused RPN IoU + RCNN IoU + feature transpose ========
// blocks 0..575: RPN; 576..607: RCNN; 608..1631: fm (B,C,HW) f32 -> (B,HW,C) bf16
__global__ __launch_bounds__(256) void k_front(
    const float* __restrict__ bboxes, const float* __restrict__ anchors,
    const float* __restrict__ nms_reg, const float* __restrict__ fm,
    int* __restrict__ tidx, u64* __restrict__ maskw,
    unsigned* __restrict__ keys, int* __restrict__ ridxg,
    u16* __restrict__ fmt) {
  __shared__ float sfm[64 * 65];
  int bid = blockIdx.x;
  if (bid < 576) {
    float* sb = sfm;
    int b = bid / 144;
    if (threadIdx.x < cT * 4) sb[threadIdx.x] = bboxes[b * cT * 4 + threadIdx.x];
    __syncthreads();
    int i = bid * 256 + threadIdx.x;
    int a = i - b * cA;
    float4 av = ((const float4*)anchors)[a];
    float at = av.x, al = av.y, ab = av.z, ar = av.w;
    float area_a = (ab - at) * (ar - al);
    float best = -1.0f; int bi = 0;
    for (int t = 0; t < cT; ++t) {
      float bt = sb[t * 4], bl = sb[t * 4 + 1], bbv = sb[t * 4 + 2], brv = sb[t * 4 + 3];
      float ih = fmaxf(fminf(bbv, ab) - fmaxf(bt, at), 0.0f);
      float iw = fmaxf(fminf(brv, ar) - fmaxf(bl, al), 0.0f);
      float inter = ih * iw;
      float a1 = (bbv - bt) * (brv - bl);
      float iou = inter / (a1 + area_a - inter);
      if (iou > best) { best = iou; bi = t; }
    }
    tidx[i] = bi;
    u64 bal = __ballot(best > 0.5f);
    if ((threadIdx.x & 63) == 0) maskw[i >> 6] = bal;
  } else if (bid < 608) {
    float* sb = sfm;
    for (int j = threadIdx.x; j < cB * cT * 4; j += 256) sb[j] = bboxes[j];
    __syncthreads();
    int i = (bid - 576) * 256 + threadIdx.x;
    if (i >= cBR) return;
    int b = i / cR;
    float4 nv = ((const float4*)nms_reg)[i];
    float nt = nv.x, nl = nv.y, nb = nv.z, nr = nv.w;
    float area_n = (nb - nt) * (nr - nl);
    float best = -1.0f; int bi = 0;
    for (int t = 0; t < cT; ++t) {
      const float* bx = &sb[(b * cT + t) * 4];
      float ih = fmaxf(fminf(bx[2], nb) - fmaxf(bx[0], nt), 0.0f);
      float iw = fmaxf(fminf(bx[3], nr) - fmaxf(bx[1], nl), 0.0f);
      float inter = ih * iw;
      float a1 = (bx[2] - bx[0]) * (bx[3] - bx[1]);
      float iou = inter / (a1 + area_n - inter);
      if (iou > best) { best = iou; bi = t; }
    }
    keys[i] = (best <= 0.5f) ? f2key(best) : POSKEY;
    ridxg[i] = bi;
  } else {
    int f = bid - 608;
    int b = f >> 8;
    int c0 = ((f >> 6) & 3) * 64;
    int p0 = (f & 63) * 64;
    int t = threadIdx.x;
    int pL = (t & 15) * 4, cL = t >> 4;
    #pragma unroll
    for (int i = 0; i < 4; ++i) {
      int c = cL + i * 16;
      float4 v = *(const float4*)&fm[((size_t)b * cC + c0 + c) * (cH * cW) + p0 + pL];
      sfm[c * 65 + pL] = v.x; sfm[c * 65 + pL + 1] = v.y;
      sfm[c * 65 + pL + 2] = v.z; sfm[c * 65 + pL + 3] = v.w;
    }
    __syncthreads();
    int pW = t >> 2, cg = (t & 3) * 16;
    unsigned pk[8];
    #pragma unroll
    for (int j = 0; j < 8; ++j) {
      unsigned lo = f2b(sfm[(cg + 2 * j) * 65 + pW]);
      unsigned hi = f2b(sfm[(cg + 2 * j + 1) * 65 + pW]);
      pk[j] = lo | (hi << 16);
    }
    u16* dst = &fmt[((size_t)b * (cH * cW) + p0 + pW) * cC + c0 + cg];
    *(uint4*)dst = *(uint4*)&pk[0];
    *(uint4*)(dst + 8) = *(uint4*)&pk[4];
  }
}

// ================= K2: fused selection (block 0: RPN, block 1: RCNN) ========
__global__ __launch_bounds__(1024) void k_select(
    const u64* __restrict__ maskw, const int* __restrict__ tidx,
    const float* __restrict__ rpn_cls, const float* __restrict__ rpn_reg,
    const float* __restrict__ bboxes, const float* __restrict__ anchors,
    const unsigned* __restrict__ keysg, const int* __restrict__ ridxg,
    const float* __restrict__ nms_reg, const int* __restrict__ classes,
    int* __restrict__ sel, int* __restrict__ cls_s,
    float* __restrict__ rois, float* __restrict__ tgt,
    float* __restrict__ out) {
  __shared__ __align__(16) char smem[50688];
  __shared__ float s_scalF[2];
  __shared__ int s_scalI[3];
  int tid = threadIdx.x, lane = tid & 63, w = tid >> 6;
  u64 lmask = (1ULL << lane) - 1ULL;

  if (blockIdx.x == 0) {
    if (tid < 4) out[2 + tid] = 0.0f;   // zero accumulators for k_heads
    u64* s_w   = (u64*)smem;
    int* s_pre = (int*)(smem + 18432);
    int* s_cw  = (int*)(smem + 19008);
    int* s_pos = (int*)(smem + 19584);
    int* s_neg = (int*)(smem + 20096);
    for (int k = tid; k < NW64; k += 1024) s_w[k] = maskw[k];
    if (tid < 128) s_pos[tid] = 0;
    if (tid < 252) s_neg[tid] = 0;
    if (tid == 0) { s_scalF[0] = 0.0f; s_scalF[1] = 0.0f; }
    __syncthreads();
    if (tid < 144) {
      int c = 0;
      #pragma unroll
      for (int k2 = 0; k2 < 16; ++k2) c += __popcll(s_w[tid * 16 + k2]);
      s_cw[tid] = c;
    }
    __syncthreads();
    if (tid == 0) {
      int run = 0;
      for (int ch = 0; ch < 144; ++ch) { s_pre[ch] = run; run += s_cw[ch]; }
    }
    __syncthreads();
    for (int ch = w; ch < 144; ch += 16) {
      int pbase = s_pre[ch];
      int nbase = ch * 1024 - pbase;
      if (pbase >= 128 && nbase >= 252) continue;
      int pc = 0;
      #pragma unroll
      for (int s2 = 0; s2 < 16; ++s2) {
        u64 word = s_w[ch * 16 + s2];
        bool m = (word >> lane) & 1ULL;
        int prefP = __popcll(word & lmask);
        int idx = ch * 1024 + s2 * 64 + lane;
        if (m) {
          int g = pbase + pc + prefP;
          if (g < 128) s_pos[g] = idx;
        } else {
          int g = nbase + (s2 * 64 + lane) - (pc + prefP);
          if (g < 252) s_neg[g] = idx;
        }
        pc += __popcll(word);
      }
    }
    __syncthreads();
    if (tid < 380) {
      int flat; float lbl;
      if (tid < 128) { flat = s_pos[tid]; lbl = 1.0f; }
      else           { flat = s_neg[tid - 128]; lbl = 0.0f; }
      float l = rpn_cls[flat];
      float term = fmaxf(l, 0.0f) - l * lbl + log1pf(expf(-fabsf(l)));
      atomicAdd(&s_scalF[0], term);
    }
    if (tid < 512) {
      int j = tid >> 2, c = tid & 3;
      int flat = s_pos[j];
      int b = flat / cA, a = flat - b * cA;
      int t = tidx[flat];
      float p = rpn_reg[flat * 4 + c];
      float tg = bboxes[(b * cT + t) * 4 + c] - anchors[a * 4 + c];
      float d = fabsf(p - tg);
      float sl = (d < 1.0f) ? 0.5f * d * d : d - 0.5f;
      atomicAdd(&s_scalF[1], sl);
    }
    __syncthreads();
    if (tid == 0) {
      out[0] = s_scalF[0] / 380.0f;
      out[1] = s_scalF[1] / 512.0f / 4.0f;
    }
  } else {
    unsigned* s_key = (unsigned*)smem;
    int* s_hist = (int*)(smem + 32000);
    int* s_pc   = (int*)(smem + 48384);
    int* s_wsum = (int*)(smem + 48896);
    int* s_wsuf = (int*)(smem + 48960);
    int* s_posr = (int*)(smem + 49024);
    int* s_negr = (int*)(smem + 49280);

    for (int i = tid; i < cBR; i += 1024) s_key[i] = keysg[i];
    if (tid < 64) s_posr[tid] = 0;
    __syncthreads();

    {
      int myv = 0; int mypre[8];
      #pragma unroll
      for (int p = 0; p < 8; ++p) {
        int i = p * 1024 + tid;
        bool v = (i < cBR) && (s_key[i] == POSKEY);
        u64 bal = __ballot(v);
        if (lane == 0) s_pc[p * 16 + w] = __popcll(bal);
        mypre[p] = __popcll(bal & lmask);
        myv |= v ? (1 << p) : 0;
      }
      __syncthreads();
      if (tid == 0) {
        int run = 0;
        for (int k = 0; k < 128; ++k) { int t = s_pc[k]; s_pc[k] = run; run += t; }
      }
      __syncthreads();
      #pragma unroll
      for (int p = 0; p < 8; ++p) {
        if (myv & (1 << p)) {
          int g = s_pc[p * 16 + w] + mypre[p];
          if (g < 64) s_posr[g] = p * 1024 + tid;
        }
      }
    }

    unsigned thr = 0; int G = 0;
    int need = cNNEG;
    #pragma unroll
    for (int lvl = 0; lvl < 3; ++lvl) {
      __syncthreads();
      #pragma unroll
      for (int k = 0; k < 4; ++k) s_hist[tid * 4 + k] = 0;
      __syncthreads();
      #pragma unroll
      for (int p = 0; p < 8; ++p) {
        int i = p * 1024 + tid;
        if (i < cBR) {
          unsigned key = s_key[i];
          int bkt = -1;
          if (lvl == 0) bkt = key >> 20;
          else if (lvl == 1) { if ((key >> 20) == (thr >> 20)) bkt = (key >> 8) & 0xFFF; }
          else { if ((key >> 8) == (thr >> 8)) bkt = (key & 0xFF) << 4; }
          if (bkt >= 0) atomicAdd(&s_hist[bkt], 1);
        }
      }
      __syncthreads();
      int local0 = s_hist[tid * 4 + 0], local1 = s_hist[tid * 4 + 1];
      int local2 = s_hist[tid * 4 + 2], local3 = s_hist[tid * 4 + 3];
      int lsum = local0 + local1 + local2 + local3;
      int x = lsum;
      #pragma unroll
      for (int off = 1; off < 64; off <<= 1) {
        int t = __shfl_down(x, off, 64);
        if (lane + off < 64) x += t;
      }
      if (lane == 0) s_wsum[w] = x;
      __syncthreads();
      if (tid == 0) {
        int run = 0;
        for (int wi = 15; wi >= 0; --wi) { s_wsuf[wi] = run; run += s_wsum[wi]; }
      }
      __syncthreads();
      int above = s_wsuf[w] + (x - lsum);
      int run = above;
      int loc[4] = {local3, local2, local1, local0};
      #pragma unroll
      for (int j = 0; j < 4; ++j) {
        int S = run + loc[j];
        if (run < need && S >= need) { s_scalI[0] = tid * 4 + (3 - j); s_scalI[1] = run; }
        run = S;
      }
      __syncthreads();
      int bS = s_scalI[0], ov = s_scalI[1];
      if (lvl == 0) thr = ((unsigned)bS) << 20;
      else if (lvl == 1) thr |= ((unsigned)bS) << 8;
      else thr |= ((unsigned)bS) >> 4;
      G += ov;
      need -= ov;
    }

    if (tid == 0) s_scalI[2] = 0;
    __syncthreads();
    #pragma unroll
    for (int p = 0; p < 8; ++p) {
      int i = p * 1024 + tid;
      if (i < cBR && s_key[i] > thr) {
        int slot = atomicAdd(&s_scalI[2], 1);
        s_negr[slot] = i;
      }
    }
    {
      __syncthreads();
      int myv = 0; int mypre[8];
      #pragma unroll
      for (int p = 0; p < 8; ++p) {
        int i = p * 1024 + tid;
        bool v = (i < cBR) && (s_key[i] == thr);
        u64 bal = __ballot(v);
        if (lane == 0) s_pc[p * 16 + w] = __popcll(bal);
        mypre[p] = __popcll(bal & lmask);
        myv |= v ? (1 << p) : 0;
      }
      __syncthreads();
      if (tid == 0) {
        int run = 0;
        for (int k = 0; k < 128; ++k) { int t = s_pc[k]; s_pc[k] = run; run += t; }
      }
      __syncthreads();
      #pragma unroll
      for (int p = 0; p < 8; ++p) {
        if (myv & (1 << p)) {
          int g = s_pc[p * 16 + w] + mypre[p];
          if (g < need) s_negr[G + g] = p * 1024 + tid;
        }
      }
    }
    __syncthreads();

    if (tid < 256) {
      int flat = (tid < 64) ? s_posr[tid] : s_negr[tid - 64];
      sel[tid] = flat;
      int b = flat / cR;
      #pragma unroll
      for (int c = 0; c < 4; ++c) rois[tid * 4 + c] = nms_reg[flat * 4 + c];
      cls_s[tid] = (tid < 64) ? classes[b * cT + ridxg[flat]] : 0;
      if (tid < 64) {
        int mt = ridxg[flat];
        #pragma unroll
        for (int c = 0; c < 4; ++c) {
          float v = nms_reg[flat * 4 + c];
          float rr = ((c < 2) ? floorf(v * 16.0f) : ceilf(v * 16.0f)) / 16.0f;
          float mbv = bboxes[(b * cT + mt) * 4 + c];
          tgt[tid * 4 + c] = mbv - rr;
        }
      }
    }
  }
}

// ================= K3: ROI align (coalesced, one block per roi x bin-row) ===
__global__ void k_roi_pool(const u16* __restrict__ fmt, const float* __restrict__ rois,
                           const int* __restrict__ sel, u16* __restrict__ feat) {
  int j = blockIdx.x;
  int py = blockIdx.y;
  int c = threadIdx.x;
  int flat = sel[j];
  int n = flat / cR;
  float t = rois[j * 4 + 0], l = rois[j * 4 + 1];
  float bb = rois[j * 4 + 2], r = rois[j * 4 + 3];
  const u16* base = fmt + (size_t)n * (cH * cW) * cC;
  float gy = (py + 0.5f) / (float)cPP;
  float ys = fminf(fmaxf(t + gy * (bb - t), 0.0f), 63.0f);
  int y0 = (int)floorf(ys);
  int y1 = min(y0 + 1, 63);
  float wy = ys - (float)y0;
  #pragma unroll
  for (int px = 0; px < cPP; ++px) {
    float gx = (px + 0.5f) / (float)cPP;
    float xs = fminf(fmaxf(l + gx * (r - l), 0.0f), 63.0f);
    int x0 = (int)floorf(xs);
    int x1 = min(x0 + 1, 63);
    float wx = xs - (float)x0;
    float f00 = b2f(base[(y0 * cW + x0) * cC + c]);
    float f01 = b2f(base[(y0 * cW + x1) * cC + c]);
    float f10 = b2f(base[(y1 * cW + x0) * cC + c]);
    float f11 = b2f(base[(y1 * cW + x1) * cC + c]);
    float v = f00 * (1.0f - wy) * (1.0f - wx) + f01 * (1.0f - wy) * wx +
              f10 * wy * (1.0f - wx) + f11 * wy * wx;
    feat[((size_t)j * 49 + py * cPP + px) * cC + c] = f2b(v);
  }
}

// ================= K4: GEMM1 feat(256x12544 bf16) @ W1(12544x1024 f32) ======
// Grid (32 n, 14 ksplit, 4 m) = 1792 blocks = 7/CU. M=64, N=32, BK=64 -> 14 iters.
// ALL prefetch state in named registers (no arrays/lambdas -> no scratch).
// 10 independent VMEM loads in flight per thread per barrier.
__global__ __launch_bounds__(256) void k_gemm1(const u16* __restrict__ feat, const float* __restrict__ W1,
                                               float* __restrict__ Cpart) {
  __shared__ u16 As[64][72];
  __shared__ u16 Bs[32][72];
  int tid = threadIdx.x;
  int n0 = blockIdx.x * 32;
  int kb0 = blockIdx.y * KCH;
  int m0 = blockIdx.z * 64;
  int lane = tid & 63, w = tid >> 6;
  int r = lane & 15, q = lane >> 4;
  f32x4 acc0 = {}, acc1 = {};

  int am = tid >> 2, aj = (tid & 3) * 16;   // A: row am, k-elems aj..aj+15
  int bn = tid & 31, bk = (tid >> 5) * 8;   // B: col bn, k-rows bk..bk+7

  const u16* ap = &feat[(size_t)(m0 + am) * cD + kb0 + aj];
  const float* bp = &W1[(size_t)(kb0 + bk) * cDH + n0 + bn];

  uint4 ra0 = *(const uint4*)ap;
  uint4 ra1 = *(const uint4*)(ap + 8);
  float f0 = bp[0], f1 = bp[cDH], f2 = bp[2 * cDH], f3 = bp[3 * cDH];
  float f4 = bp[4 * cDH], f5 = bp[5 * cDH], f6 = bp[6 * cDH], f7 = bp[7 * cDH];

  for (int it = 0; it < NITER; ++it) {
    __syncthreads();
    *(uint4*)&As[am][aj] = ra0;
    *(uint4*)&As[am][aj + 8] = ra1;
    {
      union { u16 u[8]; uint4 v; } pb;
      pb.u[0] = f2b(f0); pb.u[1] = f2b(f1); pb.u[2] = f2b(f2); pb.u[3] = f2b(f3);
      pb.u[4] = f2b(f4); pb.u[5] = f2b(f5); pb.u[6] = f2b(f6); pb.u[7] = f2b(f7);
      *(uint4*)&Bs[bn][bk] = pb.v;
    }
    __syncthreads();
    if (it + 1 < NITER) {
      ap += BK;
      bp += (size_t)BK * cDH;
      ra0 = *(const uint4*)ap;
      ra1 = *(const uint4*)(ap + 8);
      f0 = bp[0]; f1 = bp[cDH]; f2 = bp[2 * cDH]; f3 = bp[3 * cDH];
      f4 = bp[4 * cDH]; f5 = bp[5 * cDH]; f6 = bp[6 * cDH]; f7 = bp[7 * cDH];
    }
    #pragma unroll
    for (int ks = 0; ks < 2; ++ks) {
      short8 a = *(const short8*)&As[w * 16 + r][ks * 32 + q * 8];
      short8 b0v = *(const short8*)&Bs[r][ks * 32 + q * 8];
      short8 b1v = *(const short8*)&Bs[16 + r][ks * 32 + q * 8];
      acc0 = __builtin_amdgcn_mfma_f32_16x16x32_bf16(a, b0v, acc0, 0, 0, 0);
      acc1 = __builtin_amdgcn_mfma_f32_16x16x32_bf16(a, b1v, acc1, 0, 0, 0);
    }
  }

  float* Cp = Cpart + (size_t)blockIdx.y * 256 * cDH;
  #pragma unroll
  for (int rg = 0; rg < 4; ++rg) {
    int row = m0 + w * 16 + q * 4 + rg;
    Cp[(size_t)row * cDH + n0 + r] = acc0[rg];
    Cp[(size_t)row * cDH + n0 + 16 + r] = acc1[rg];
  }
}

// ================= K5: heads + final losses (one block per roi row) =========
__global__ __launch_bounds__(256) void k_heads(
    const float* __restrict__ Cpart, const float* __restrict__ b1,
    const float* __restrict__ Wr, const float* __restrict__ br,
    const float* __restrict__ Wc, const float* __restrict__ bc,
    const int* __restrict__ cls_s, const float* __restrict__ tgt,
    float* __restrict__ out) {
  __shared__ float sacc[25];
  int row = blockIdx.x, tid = threadIdx.x, lane = tid & 63;
  if (tid < 25) sacc[tid] = 0.0f;
  __syncthreads();
  int k0 = tid * 4;
  float4 h = *(const float4*)&b1[k0];
  #pragma unroll
  for (int s = 0; s < SPLITS; ++s) {
    float4 c = *(const float4*)&Cpart[(size_t)s * 256 * cDH + (size_t)row * cDH + k0];
    h.x += c.x; h.y += c.y; h.z += c.z; h.w += c.w;
  }
  float hv[4] = {fmaxf(h.x, 0.f), fmaxf(h.y, 0.f), fmaxf(h.z, 0.f), fmaxf(h.w, 0.f)};
  float part[25];
  #pragma unroll
  for (int c = 0; c < 25; ++c) part[c] = 0.0f;
  #pragma unroll
  for (int j = 0; j < 4; ++j) {
    float4 wr = *(const float4*)&Wr[(k0 + j) * 4];
    part[0] += hv[j] * wr.x; part[1] += hv[j] * wr.y;
    part[2] += hv[j] * wr.z; part[3] += hv[j] * wr.w;
    const float* wc = &Wc[(k0 + j) * 21];
    #pragma unroll
    for (int c = 0; c < 21; ++c) part[4 + c] += hv[j] * wc[c];
  }
  #pragma unroll
  for (int off = 32; off; off >>= 1) {
    #pragma unroll
    for (int c = 0; c < 25; ++c) part[c] += __shfl_down(part[c], off, 64);
  }
  if (lane == 0) {
    #pragma unroll
    for (int c = 0; c < 25; ++c) atomicAdd(&sacc[c], part[c]);
  }
  __syncthreads();
  if (tid == 0) {
    int cls = cls_s[row];
    float m = -INFINITY;
    float vals[21];
    #pragma unroll
    for (int c = 0; c < 21; ++c) { vals[c] = sacc[4 + c] + bc[c]; m = fmaxf(m, vals[c]); }
    float sum = 0.0f;
    #pragma unroll
    for (int c = 0; c < 21; ++c) sum += expf(vals[c] - m);
    float lse = m + logf(sum);
    atomicAdd(&out[2], (lse - vals[cls]) * (1.0f / 256.0f));
    if (row < 64) {
      int am2 = 0; float bv = vals[0];
      #pragma unroll
      for (int c = 1; c < 21; ++c) if (vals[c] > bv) { bv = vals[c]; am2 = c; }
      if (am2 == cls) atomicAdd(&out[4], 1.0f / 64.0f);
    }
  }
  if (tid == 1 && row < 64) {
    float sl = 0.0f, of = 0.0f;
    #pragma unroll
    for (int c = 0; c < 4; ++c) {
      float d = fabsf((sacc[c] + br[c]) - tgt[row * 4 + c]);
      sl += (d < 1.0f) ? 0.5f * d * d : d - 0.5f;
      of += d;
    }
    atomicAdd(&out[3], sl * (1.0f / 256.0f));
    atomicAdd(&out[5], of * (1.0f / 256.0f));
  }
}

// ================= launch =================
extern "C" void kernel_launch(void* const* d_in, const int* in_sizes, int n_in,
                              void* d_out, int out_size, void* d_ws, size_t ws_size,
                              hipStream_t stream) {
  const float* nms_reg = (const float*)d_in[0];
  const float* fm      = (const float*)d_in[2];
  const float* bboxes  = (const float*)d_in[3];
  const int*   classes = (const int*)d_in[4];
  const float* anchors = (const float*)d_in[5];
  const float* rpn_reg = (const float*)d_in[6];
  const float* rpn_cls = (const float*)d_in[7];
  const float* W1      = (const float*)d_in[8];
  const float* b1      = (const float*)d_in[9];
  const float* Wr      = (const float*)d_in[10];
  const float* br      = (const float*)d_in[11];
  const float* Wc      = (const float*)d_in[12];
  const float* bc      = (const float*)d_in[13];
  float* out = (float*)d_out;
  char* ws = (char*)d_ws;

  int*      tidx  = (int*)(ws + O_TIDX);
  u64*      maskw = (u64*)(ws + O_MASKW);
  unsigned* keys  = (unsigned*)(ws + O_KEYS);
  int*      ridxg = (int*)(ws + O_RIDXG);
  int*      sel   = (int*)(ws + O_SEL);
  int*      clss  = (int*)(ws + O_CLS);
  float*    rois  = (float*)(ws + O_ROIS);
  float*    tgt   = (float*)(ws + O_TGT);
  u16*      fmt   = (u16*)(ws + O_FMT);
  u16*      feat  = (u16*)(ws + O_FEAT);
  float*    Cpart = (float*)(ws + O_CPART);

  k_front<<<608 + 1024, 256, 0, stream>>>(bboxes, anchors, nms_reg, fm,
                                          tidx, maskw, keys, ridxg, fmt);
  k_select<<<2, 1024, 0, stream>>>(maskw, tidx, rpn_cls, rpn_reg, bboxes, anchors,
                                   keys, ridxg, nms_reg, classes, sel, clss, rois, tgt, out);
  k_roi_pool<<<dim3(256, cPP), 256, 0, stream>>>(fmt, rois, sel, feat);
  k_gemm1<<<dim3(32, SPLITS, 4), 256, 0, stream>>>(feat, W1, Cpart);
  k_heads<<<256, 256, 0, stream>>>(Cpart, b1, Wr, br, Wc, bc, clss, tgt, out);
}